// Round 8
// baseline (409.378 us; speedup 1.0000x reference)
//
#include <hip/hip_runtime.h>

#define HID 64
#define NGRAPHS 256
#define SCAN_ELEMS 1024   // elements per scan block (256 thr x 4)
#define DEGPAD 16         // one deg counter per 64B line (returning-atomic
                          // per-line serialization: R6/R7 measured 53.5us
                          // invariant to 1 vs 8 chains/thread -> line-bound)

// ---- hist + rank: rank[i] = within-row arrival order of edge i ----------

__global__ __launch_bounds__(256) void k_hist(const int* __restrict__ dst,
                                              int* __restrict__ deg,
                                              int* __restrict__ rank, int e) {
    int base = (blockIdx.x * 256 + threadIdx.x) * 2;
    if (base + 1 < e) {
        int2 d2 = *(const int2*)(dst + base);
        int r0 = atomicAdd(&deg[(size_t)d2.x * DEGPAD], 1);
        int r1 = atomicAdd(&deg[(size_t)d2.y * DEGPAD], 1);
        *(int2*)(rank + base) = make_int2(r0, r1);
    } else if (base < e) {
        rank[base] = atomicAdd(&deg[(size_t)dst[base] * DEGPAD], 1);
    }
}

// ---- scan stage 1 (+ dinv fused): per-block exclusive scan over n1=N+1 --
// deg is DEGPAD-strided.

__global__ __launch_bounds__(256) void k_scan1(const int* __restrict__ deg,
                                               int* __restrict__ rowptr,
                                               int* __restrict__ bsum,
                                               float* __restrict__ dinv,
                                               int n1) {
    __shared__ int sh[256];
    const int t = threadIdx.x;
    const int base = blockIdx.x * SCAN_ELEMS + t * 4;
    int v[4];
    int s = 0;
#pragma unroll
    for (int k = 0; k < 4; k++) {
        int i = base + k;
        v[k] = (i < n1) ? deg[(size_t)i * DEGPAD] : 0;
        if (i < n1 - 1) dinv[i] = rsqrtf((float)(v[k] + 1));  // +1 self-loop
        s += v[k];
    }
    sh[t] = s;
    __syncthreads();
#pragma unroll
    for (int off = 1; off < 256; off <<= 1) {
        int add = (t >= off) ? sh[t - off] : 0;
        __syncthreads();
        sh[t] += add;
        __syncthreads();
    }
    int run = sh[t] - s;    // exclusive prefix of this thread's chunk
#pragma unroll
    for (int k = 0; k < 4; k++) {
        int i = base + k;
        if (i < n1) rowptr[i] = run;
        run += v[k];
    }
    if (t == 255) bsum[blockIdx.x] = sh[255];
}

// ---- scan stage 2: exclusive scan of (<=128) block totals ---------------

__global__ __launch_bounds__(128) void k_scan2(int* __restrict__ bsum, int nb) {
    __shared__ int sh[128];
    const int t = threadIdx.x;
    int own = (t < nb) ? bsum[t] : 0;
    sh[t] = own;
    __syncthreads();
#pragma unroll
    for (int off = 1; off < 128; off <<= 1) {
        int add = (t >= off) ? sh[t - off] : 0;
        __syncthreads();
        sh[t] += add;
        __syncthreads();
    }
    if (t < nb) bsum[t] = sh[t] - own;
}

// ---- fill: NO atomic. pos = rowptr[d] + bsum[d>>10] + rank. 4 edges/thr -

__global__ __launch_bounds__(256) void k_fill(const int* __restrict__ src,
                                              const int* __restrict__ dst,
                                              const int* __restrict__ rank,
                                              const int* __restrict__ rowptr,
                                              const int* __restrict__ bsum,
                                              const float* __restrict__ dinv,
                                              int2* __restrict__ csr, int e) {
    int base = (blockIdx.x * 256 + threadIdx.x) * 4;
    if (base + 3 < e) {
        int4 s4 = *(const int4*)(src + base);
        int4 d4 = *(const int4*)(dst + base);
        int4 r4 = *(const int4*)(rank + base);
        int s[4] = {s4.x, s4.y, s4.z, s4.w};
        int d[4] = {d4.x, d4.y, d4.z, d4.w};
        int r[4] = {r4.x, r4.y, r4.z, r4.w};
#pragma unroll
        for (int k = 0; k < 4; k++) {
            int pos = rowptr[d[k]] + bsum[d[k] >> 10] + r[k];
            float w = dinv[s[k]] * dinv[d[k]];
            csr[pos] = make_int2(s[k], __float_as_int(w));
        }
    } else {
        for (int i = base; i < e; i++) {
            int s = src[i], d = dst[i];
            int pos = rowptr[d] + bsum[d >> 10] + rank[i];
            csr[pos] = make_int2(s, __float_as_int(dinv[s] * dinv[d]));
        }
    }
}

// ---- per-layer dense transform: h = (relu?)act @ W ----------------------

template <int K, bool RELU>
__global__ __launch_bounds__(256) void k_gemm(
        const float* __restrict__ act, const float* __restrict__ W,
        float* __restrict__ h, int n_nodes) {
    __shared__ float Wsh[K * HID];
    __shared__ float Ash[16 * K];
    const int t = threadIdx.x;
    const int n0 = blockIdx.x * 16;

    for (int i = t; i < K * HID; i += 256) Wsh[i] = W[i];
    const long long lim = (long long)(n_nodes - n0) * K;
    for (int i = t; i < 16 * K; i += 256) {
        float v = (i < lim) ? act[(size_t)n0 * K + i] : 0.0f;
        if (RELU) v = fmaxf(v, 0.0f);
        Ash[i] = v;
    }
    __syncthreads();

    const int c = t & 63;       // output channel
    const int g = t >> 6;       // node sub-group 0..3, 4 nodes each
    float acc[4] = {0.0f, 0.0f, 0.0f, 0.0f};
#pragma unroll 8
    for (int k = 0; k < K; k++) {
        float w = Wsh[k * HID + c];
#pragma unroll
        for (int i = 0; i < 4; i++) acc[i] += Ash[(g * 4 + i) * K + k] * w;
    }
#pragma unroll
    for (int i = 0; i < 4; i++) {
        int n = n0 + g * 4 + i;
        if (n < n_nodes) h[(size_t)n * HID + c] = acc[i];
    }
}

// ---- CSR aggregate: float4 lanes, 16 lanes/node, 4 nodes/wave, 4-wide ---
// acc starts at b + h*dinv^2 (bias + self-loop folded here).

__global__ __launch_bounds__(256) void k_aggregate(
        const int* __restrict__ rowptr,      // exclusive, N+1 entries (partial)
        const int* __restrict__ bsum,
        const int2* __restrict__ csr,
        const float* __restrict__ h, const float* __restrict__ b,
        const float* __restrict__ dinv, float* __restrict__ agg, int n_nodes) {
    int gtid = blockIdx.x * 256 + threadIdx.x;
    int node = (gtid >> 6) * 4 + ((threadIdx.x >> 4) & 3);
    int l16 = threadIdx.x & 15;
    if (node >= n_nodes) return;
    int beg = rowptr[node] + bsum[node >> 10];
    int end = rowptr[node + 1] + bsum[(node + 1) >> 10];
    const float4* h4 = (const float4*)h;
    const float4* b4 = (const float4*)b;
    float dv = dinv[node];
    float sc = dv * dv;
    float4 hb = h4[(size_t)node * 16 + l16];
    float4 bb = b4[l16];
    float4 acc = make_float4(bb.x + hb.x * sc, bb.y + hb.y * sc,
                             bb.z + hb.z * sc, bb.w + hb.w * sc);
    int j = beg;
    for (; j + 3 < end; j += 4) {
        int2 e0 = csr[j], e1 = csr[j + 1], e2 = csr[j + 2], e3 = csr[j + 3];
        float4 v0 = h4[(size_t)e0.x * 16 + l16];
        float4 v1 = h4[(size_t)e1.x * 16 + l16];
        float4 v2 = h4[(size_t)e2.x * 16 + l16];
        float4 v3 = h4[(size_t)e3.x * 16 + l16];
        float w0 = __int_as_float(e0.y), w1 = __int_as_float(e1.y);
        float w2 = __int_as_float(e2.y), w3 = __int_as_float(e3.y);
        acc.x += v0.x * w0 + v1.x * w1 + v2.x * w2 + v3.x * w3;
        acc.y += v0.y * w0 + v1.y * w1 + v2.y * w2 + v3.y * w3;
        acc.z += v0.z * w0 + v1.z * w1 + v2.z * w2 + v3.z * w3;
        acc.w += v0.w * w0 + v1.w * w1 + v2.w * w2 + v3.w * w3;
    }
    for (; j < end; j++) {
        int2 e0 = csr[j];
        float4 v = h4[(size_t)e0.x * 16 + l16];
        float w = __int_as_float(e0.y);
        acc.x += v.x * w; acc.y += v.y * w; acc.z += v.z * w; acc.w += v.w * w;
    }
    ((float4*)agg)[(size_t)node * 16 + l16] = acc;
}

// ---- fused mean-pool + head: one block per graph, batch sorted ----------
// Binary-search the node range, block-reduce 64 channels, apply Wl/bl.
// No atomics, no init memset, no separate head dispatch.

__global__ __launch_bounds__(256) void k_pool_head(
        const float* __restrict__ agg, const int* __restrict__ batch,
        const float* __restrict__ Wl, const float* __restrict__ bl,
        float* __restrict__ out, int n_nodes) {
    int g = blockIdx.x;
    int lo = 0, hi = n_nodes;
    while (lo < hi) { int m = (lo + hi) >> 1; if (batch[m] < g) lo = m + 1; else hi = m; }
    int nstart = lo;
    hi = n_nodes;
    while (lo < hi) { int m = (lo + hi) >> 1; if (batch[m] < g + 1) lo = m + 1; else hi = m; }
    int nend = lo;

    int c = threadIdx.x & 63, part = threadIdx.x >> 6;
    float acc = 0.0f;
    for (int n = nstart + part; n < nend; n += 4)
        acc += agg[(size_t)n * HID + c];

    __shared__ float red[4][64];
    __shared__ float hd[128];
    red[part][c] = acc;
    __syncthreads();
    if (threadIdx.x < 64) {
        float cntf = (float)(nend - nstart);
        float pooled = (red[0][c] + red[1][c] + red[2][c] + red[3][c])
                       / fmaxf(cntf, 1.0f);
        hd[c] = pooled * Wl[c * 2 + 0];
        hd[64 + c] = pooled * Wl[c * 2 + 1];
    }
    __syncthreads();
    if (threadIdx.x < 2) {
        float s = 0.0f;
        for (int k = 0; k < 64; k++) s += hd[threadIdx.x * 64 + k];
        out[g * 2 + threadIdx.x] = s + bl[threadIdx.x];
    }
}

// -------------------------------------------------------------------------

extern "C" void kernel_launch(void* const* d_in, const int* in_sizes, int n_in,
                              void* d_out, int out_size, void* d_ws, size_t ws_size,
                              hipStream_t stream) {
    const float* x     = (const float*)d_in[0];
    const int*   ei    = (const int*)d_in[1];
    const int*   batch = (const int*)d_in[2];
    const float* W1    = (const float*)d_in[3];
    const float* b1    = (const float*)d_in[4];
    const float* W2    = (const float*)d_in[5];
    const float* b2    = (const float*)d_in[6];
    const float* W3    = (const float*)d_in[7];
    const float* b3    = (const float*)d_in[8];
    const float* Wl    = (const float*)d_in[9];
    const float* bl    = (const float*)d_in[10];
    float* out = (float*)d_out;

    const int N = in_sizes[0] / 7;     // 100000
    const int E = in_sizes[1] / 2;     // 1250000
    const int* src = ei;
    const int* dst = ei + E;

    // workspace carve-out (256B aligned)
    char* ws = (char*)d_ws;
    size_t off = 0;
    auto carve = [&](size_t bytes) {
        void* p = ws + off;
        off = (off + bytes + 255) & ~(size_t)255;
        return p;
    };
    int*   deg_i   = (int*)carve((size_t)(N + 1) * DEGPAD * 4);
    float* dinv    = (float*)carve((size_t)N * 4);
    int*   rowptr  = (int*)carve((size_t)(N + 1) * 4);
    int*   bsum    = (int*)carve(512 * 4);
    int*   rank    = (int*)carve((size_t)E * 4);
    int2*  csr     = (int2*)carve((size_t)E * 8);
    float* bufH    = (float*)carve((size_t)N * HID * 4);
    float* bufA    = (float*)carve((size_t)N * HID * 4);

    const int nb_gemm = (N + 15) / 16;                           // 6250
    const int nb_scan = (N + 1 + SCAN_ELEMS - 1) / SCAN_ELEMS;   // 98
    const int nb_hist = (E / 2 + 255) / 256;
    const int nb_fill = (E / 4 + 255) / 256;
    const int nb_agg  = (N + 15) / 16;     // 16 nodes per block (4/wave)

    // ---- CSR build (once, reused by all 3 layers)
    hipMemsetAsync(deg_i, 0, (size_t)(N + 1) * DEGPAD * 4, stream);
    k_hist<<<nb_hist, 256, 0, stream>>>(dst, deg_i, rank, E);
    k_scan1<<<nb_scan, 256, 0, stream>>>(deg_i, rowptr, bsum, dinv, N + 1);
    k_scan2<<<1, 128, 0, stream>>>(bsum, nb_scan);
    k_fill<<<nb_fill, 256, 0, stream>>>(src, dst, rank, rowptr, bsum, dinv, csr, E);

    // ---- layer 1: x (N x 7) -> bufH; aggregate -> bufA
    k_gemm<7, false><<<nb_gemm, 256, 0, stream>>>(x, W1, bufH, N);
    k_aggregate<<<nb_agg, 256, 0, stream>>>(rowptr, bsum, csr, bufH, b1, dinv, bufA, N);

    // ---- layer 2: relu(bufA) @ W2 -> bufH; aggregate -> bufA
    k_gemm<HID, true><<<nb_gemm, 256, 0, stream>>>(bufA, W2, bufH, N);
    k_aggregate<<<nb_agg, 256, 0, stream>>>(rowptr, bsum, csr, bufH, b2, dinv, bufA, N);

    // ---- layer 3
    k_gemm<HID, true><<<nb_gemm, 256, 0, stream>>>(bufA, W3, bufH, N);
    k_aggregate<<<nb_agg, 256, 0, stream>>>(rowptr, bsum, csr, bufH, b3, dinv, bufA, N);

    // ---- fused mean-pool + head (one block per graph)
    k_pool_head<<<NGRAPHS, 256, 0, stream>>>(bufA, batch, Wl, bl, out, N);
}

// Round 9
// 361.028 us; speedup vs baseline: 1.1339x; 1.1339x over previous
//
#include <hip/hip_runtime.h>
#include <hip/hip_fp16.h>

#define HID 64
#define NGRAPHS 256
#define SCAN_ELEMS 1024   // elements per scan block (256 thr x 4)

// NOTE (R6-R8 measured): scattered returning atomics are memory-side
// (cross-XCD coherence) at ~24 G sectors/s regardless of padding or
// chains/thread -> k_hist ~51us is an atomic-unit floor, not contention.

// ---- hist + rank: rank[i] = within-row arrival order of edge i ----------

__global__ __launch_bounds__(256) void k_hist(const int* __restrict__ dst,
                                              int* __restrict__ deg,
                                              int* __restrict__ rank, int e) {
    int base = (blockIdx.x * 256 + threadIdx.x) * 2;
    if (base + 1 < e) {
        int2 d2 = *(const int2*)(dst + base);
        int r0 = atomicAdd(&deg[d2.x], 1);
        int r1 = atomicAdd(&deg[d2.y], 1);
        *(int2*)(rank + base) = make_int2(r0, r1);
    } else if (base < e) {
        rank[base] = atomicAdd(&deg[dst[base]], 1);
    }
}

// ---- scan stage 1 (+ dinv fused): per-block exclusive scan over n1=N+1 --

__global__ __launch_bounds__(256) void k_scan1(const int* __restrict__ deg,
                                               int* __restrict__ rowptr,
                                               int* __restrict__ bsum,
                                               float* __restrict__ dinv,
                                               int n1) {
    __shared__ int sh[256];
    const int t = threadIdx.x;
    const int base = blockIdx.x * SCAN_ELEMS + t * 4;
    int v[4];
    int s = 0;
#pragma unroll
    for (int k = 0; k < 4; k++) {
        int i = base + k;
        v[k] = (i < n1) ? deg[i] : 0;
        if (i < n1 - 1) dinv[i] = rsqrtf((float)(v[k] + 1));  // +1 self-loop
        s += v[k];
    }
    sh[t] = s;
    __syncthreads();
#pragma unroll
    for (int off = 1; off < 256; off <<= 1) {
        int add = (t >= off) ? sh[t - off] : 0;
        __syncthreads();
        sh[t] += add;
        __syncthreads();
    }
    int run = sh[t] - s;    // exclusive prefix of this thread's chunk
#pragma unroll
    for (int k = 0; k < 4; k++) {
        int i = base + k;
        if (i < n1) rowptr[i] = run;
        run += v[k];
    }
    if (t == 255) bsum[blockIdx.x] = sh[255];
}

// ---- scan stage 2: exclusive scan of (<=128) block totals ---------------

__global__ __launch_bounds__(128) void k_scan2(int* __restrict__ bsum, int nb) {
    __shared__ int sh[128];
    const int t = threadIdx.x;
    int own = (t < nb) ? bsum[t] : 0;
    sh[t] = own;
    __syncthreads();
#pragma unroll
    for (int off = 1; off < 128; off <<= 1) {
        int add = (t >= off) ? sh[t - off] : 0;
        __syncthreads();
        sh[t] += add;
        __syncthreads();
    }
    if (t < nb) bsum[t] = sh[t] - own;
}

// ---- fill: NO atomic. pos = rowptr[d] + bsum[d>>10] + rank. 4 edges/thr -

__global__ __launch_bounds__(256) void k_fill(const int* __restrict__ src,
                                              const int* __restrict__ dst,
                                              const int* __restrict__ rank,
                                              const int* __restrict__ rowptr,
                                              const int* __restrict__ bsum,
                                              const float* __restrict__ dinv,
                                              int2* __restrict__ csr, int e) {
    int base = (blockIdx.x * 256 + threadIdx.x) * 4;
    if (base + 3 < e) {
        int4 s4 = *(const int4*)(src + base);
        int4 d4 = *(const int4*)(dst + base);
        int4 r4 = *(const int4*)(rank + base);
        int s[4] = {s4.x, s4.y, s4.z, s4.w};
        int d[4] = {d4.x, d4.y, d4.z, d4.w};
        int r[4] = {r4.x, r4.y, r4.z, r4.w};
#pragma unroll
        for (int k = 0; k < 4; k++) {
            int pos = rowptr[d[k]] + bsum[d[k] >> 10] + r[k];
            float w = dinv[s[k]] * dinv[d[k]];
            csr[pos] = make_int2(s[k], __float_as_int(w));
        }
    } else {
        for (int i = base; i < e; i++) {
            int s = src[i], d = dst[i];
            int pos = rowptr[d] + bsum[d >> 10] + rank[i];
            csr[pos] = make_int2(s, __float_as_int(dinv[s] * dinv[d]));
        }
    }
}

// ---- per-layer dense transform: h = (relu?)act @ W, h stored fp16 -------

template <int K, bool RELU>
__global__ __launch_bounds__(256) void k_gemm(
        const float* __restrict__ act, const float* __restrict__ W,
        __half* __restrict__ h, int n_nodes) {
    __shared__ float Wsh[K * HID];
    __shared__ float Ash[16 * K];
    const int t = threadIdx.x;
    const int n0 = blockIdx.x * 16;

    for (int i = t; i < K * HID; i += 256) Wsh[i] = W[i];
    const long long lim = (long long)(n_nodes - n0) * K;
    for (int i = t; i < 16 * K; i += 256) {
        float v = (i < lim) ? act[(size_t)n0 * K + i] : 0.0f;
        if (RELU) v = fmaxf(v, 0.0f);
        Ash[i] = v;
    }
    __syncthreads();

    const int c = t & 63;       // output channel
    const int g = t >> 6;       // node sub-group 0..3, 4 nodes each
    float acc[4] = {0.0f, 0.0f, 0.0f, 0.0f};
#pragma unroll 8
    for (int k = 0; k < K; k++) {
        float w = Wsh[k * HID + c];
#pragma unroll
        for (int i = 0; i < 4; i++) acc[i] += Ash[(g * 4 + i) * K + k] * w;
    }
#pragma unroll
    for (int i = 0; i < 4; i++) {
        int n = n0 + g * 4 + i;
        if (n < n_nodes) h[(size_t)n * HID + c] = __float2half(acc[i]);
    }
}

// ---- CSR aggregate: fp16 h rows (128B), 16 lanes/node, 4 nodes/wave -----
// Each lane owns 4 channels = one 8B load per gathered row. acc fp32,
// starts at b + h*dinv^2 (bias + self-loop folded here).

__device__ __forceinline__ float4 h4_to_f4(int2 raw) {
    __half2 p0 = *(__half2*)&raw.x;
    __half2 p1 = *(__half2*)&raw.y;
    float2 f0 = __half22float2(p0);
    float2 f1 = __half22float2(p1);
    return make_float4(f0.x, f0.y, f1.x, f1.y);
}

__global__ __launch_bounds__(256) void k_aggregate(
        const int* __restrict__ rowptr,      // exclusive, N+1 entries (partial)
        const int* __restrict__ bsum,
        const int2* __restrict__ csr,
        const __half* __restrict__ h, const float* __restrict__ b,
        const float* __restrict__ dinv, float* __restrict__ agg, int n_nodes) {
    int gtid = blockIdx.x * 256 + threadIdx.x;
    int node = (gtid >> 6) * 4 + ((threadIdx.x >> 4) & 3);
    int l16 = threadIdx.x & 15;
    if (node >= n_nodes) return;
    int beg = rowptr[node] + bsum[node >> 10];
    int end = rowptr[node + 1] + bsum[(node + 1) >> 10];
    const int2* h8 = (const int2*)h;         // 4 halves per int2; 16 per row
    const float4* b4 = (const float4*)b;
    float dv = dinv[node];
    float sc = dv * dv;
    float4 hb = h4_to_f4(h8[(size_t)node * 16 + l16]);
    float4 bb = b4[l16];
    float4 acc = make_float4(bb.x + hb.x * sc, bb.y + hb.y * sc,
                             bb.z + hb.z * sc, bb.w + hb.w * sc);
    int j = beg;
    for (; j + 3 < end; j += 4) {
        int2 e0 = csr[j], e1 = csr[j + 1], e2 = csr[j + 2], e3 = csr[j + 3];
        int2 r0 = h8[(size_t)e0.x * 16 + l16];
        int2 r1 = h8[(size_t)e1.x * 16 + l16];
        int2 r2 = h8[(size_t)e2.x * 16 + l16];
        int2 r3 = h8[(size_t)e3.x * 16 + l16];
        float4 v0 = h4_to_f4(r0), v1 = h4_to_f4(r1);
        float4 v2 = h4_to_f4(r2), v3 = h4_to_f4(r3);
        float w0 = __int_as_float(e0.y), w1 = __int_as_float(e1.y);
        float w2 = __int_as_float(e2.y), w3 = __int_as_float(e3.y);
        acc.x += v0.x * w0 + v1.x * w1 + v2.x * w2 + v3.x * w3;
        acc.y += v0.y * w0 + v1.y * w1 + v2.y * w2 + v3.y * w3;
        acc.z += v0.z * w0 + v1.z * w1 + v2.z * w2 + v3.z * w3;
        acc.w += v0.w * w0 + v1.w * w1 + v2.w * w2 + v3.w * w3;
    }
    for (; j < end; j++) {
        int2 e0 = csr[j];
        float4 v = h4_to_f4(h8[(size_t)e0.x * 16 + l16]);
        float w = __int_as_float(e0.y);
        acc.x += v.x * w; acc.y += v.y * w; acc.z += v.z * w; acc.w += v.w * w;
    }
    ((float4*)agg)[(size_t)node * 16 + l16] = acc;
}

// ---- fused mean-pool + head: one block per graph, batch sorted ----------

__global__ __launch_bounds__(256) void k_pool_head(
        const float* __restrict__ agg, const int* __restrict__ batch,
        const float* __restrict__ Wl, const float* __restrict__ bl,
        float* __restrict__ out, int n_nodes) {
    int g = blockIdx.x;
    int lo = 0, hi = n_nodes;
    while (lo < hi) { int m = (lo + hi) >> 1; if (batch[m] < g) lo = m + 1; else hi = m; }
    int nstart = lo;
    hi = n_nodes;
    while (lo < hi) { int m = (lo + hi) >> 1; if (batch[m] < g + 1) lo = m + 1; else hi = m; }
    int nend = lo;

    int c = threadIdx.x & 63, part = threadIdx.x >> 6;
    float acc = 0.0f;
    for (int n = nstart + part; n < nend; n += 4)
        acc += agg[(size_t)n * HID + c];

    __shared__ float red[4][64];
    __shared__ float hd[128];
    red[part][c] = acc;
    __syncthreads();
    if (threadIdx.x < 64) {
        float cntf = (float)(nend - nstart);
        float pooled = (red[0][c] + red[1][c] + red[2][c] + red[3][c])
                       / fmaxf(cntf, 1.0f);
        hd[c] = pooled * Wl[c * 2 + 0];
        hd[64 + c] = pooled * Wl[c * 2 + 1];
    }
    __syncthreads();
    if (threadIdx.x < 2) {
        float s = 0.0f;
        for (int k = 0; k < 64; k++) s += hd[threadIdx.x * 64 + k];
        out[g * 2 + threadIdx.x] = s + bl[threadIdx.x];
    }
}

// -------------------------------------------------------------------------

extern "C" void kernel_launch(void* const* d_in, const int* in_sizes, int n_in,
                              void* d_out, int out_size, void* d_ws, size_t ws_size,
                              hipStream_t stream) {
    const float* x     = (const float*)d_in[0];
    const int*   ei    = (const int*)d_in[1];
    const int*   batch = (const int*)d_in[2];
    const float* W1    = (const float*)d_in[3];
    const float* b1    = (const float*)d_in[4];
    const float* W2    = (const float*)d_in[5];
    const float* b2    = (const float*)d_in[6];
    const float* W3    = (const float*)d_in[7];
    const float* b3    = (const float*)d_in[8];
    const float* Wl    = (const float*)d_in[9];
    const float* bl    = (const float*)d_in[10];
    float* out = (float*)d_out;

    const int N = in_sizes[0] / 7;     // 100000
    const int E = in_sizes[1] / 2;     // 1250000
    const int* src = ei;
    const int* dst = ei + E;

    // workspace carve-out (256B aligned)
    char* ws = (char*)d_ws;
    size_t off = 0;
    auto carve = [&](size_t bytes) {
        void* p = ws + off;
        off = (off + bytes + 255) & ~(size_t)255;
        return p;
    };
    int*    deg_i  = (int*)carve((size_t)(N + 1) * 4);
    float*  dinv   = (float*)carve((size_t)N * 4);
    int*    rowptr = (int*)carve((size_t)(N + 1) * 4);
    int*    bsum   = (int*)carve(512 * 4);
    int*    rank   = (int*)carve((size_t)E * 4);
    int2*   csr    = (int2*)carve((size_t)E * 8);
    __half* bufH   = (__half*)carve((size_t)N * HID * 2);
    float*  bufA   = (float*)carve((size_t)N * HID * 4);

    const int nb_gemm = (N + 15) / 16;                           // 6250
    const int nb_scan = (N + 1 + SCAN_ELEMS - 1) / SCAN_ELEMS;   // 98
    const int nb_hist = (E / 2 + 255) / 256;
    const int nb_fill = (E / 4 + 255) / 256;
    const int nb_agg  = (N + 15) / 16;     // 16 nodes per block (4/wave)

    // ---- CSR build (once, reused by all 3 layers)
    hipMemsetAsync(deg_i, 0, (size_t)(N + 1) * 4, stream);
    k_hist<<<nb_hist, 256, 0, stream>>>(dst, deg_i, rank, E);
    k_scan1<<<nb_scan, 256, 0, stream>>>(deg_i, rowptr, bsum, dinv, N + 1);
    k_scan2<<<1, 128, 0, stream>>>(bsum, nb_scan);
    k_fill<<<nb_fill, 256, 0, stream>>>(src, dst, rank, rowptr, bsum, dinv, csr, E);

    // ---- layer 1: x (N x 7) -> bufH (fp16); aggregate -> bufA
    k_gemm<7, false><<<nb_gemm, 256, 0, stream>>>(x, W1, bufH, N);
    k_aggregate<<<nb_agg, 256, 0, stream>>>(rowptr, bsum, csr, bufH, b1, dinv, bufA, N);

    // ---- layer 2: relu(bufA) @ W2 -> bufH; aggregate -> bufA
    k_gemm<HID, true><<<nb_gemm, 256, 0, stream>>>(bufA, W2, bufH, N);
    k_aggregate<<<nb_agg, 256, 0, stream>>>(rowptr, bsum, csr, bufH, b2, dinv, bufA, N);

    // ---- layer 3
    k_gemm<HID, true><<<nb_gemm, 256, 0, stream>>>(bufA, W3, bufH, N);
    k_aggregate<<<nb_agg, 256, 0, stream>>>(rowptr, bsum, csr, bufH, b3, dinv, bufA, N);

    // ---- fused mean-pool + head (one block per graph)
    k_pool_head<<<NGRAPHS, 256, 0, stream>>>(bufA, batch, Wl, bl, out, N);
}

// Round 10
// 315.795 us; speedup vs baseline: 1.2963x; 1.1432x over previous
//
#include <hip/hip_runtime.h>
#include <hip/hip_fp16.h>

#define HID 64
#define NGRAPHS 256
#define CHUNK 8192        // edges per pass-1 block
#define BKTSZ 512         // nodes per coarse bucket
#define BKTSH 9
#define PSH 17            // src fits in 17 bits (N <= 131072)
#define PMASK 0x1FFFF
#define SCAN_ELEMS 1024

// R6-R9 measured: scattered global atomics / scattered 4-8B stores write
// through ~64B lines at ~0.9 TB/s (memory-side, parallelism-invariant).
// => CSR build must keep contended counters in LDS and write only
// coalesced runs / L2-local segments. Two-level counting sort below.

// ---- pass 1a: per-chunk coarse histogram (LDS) -> H[bkt*nchunk + chunk] --

__global__ __launch_bounds__(256) void k_bucket_count(
        const int* __restrict__ dst, int* __restrict__ H,
        int e, int nbkt, int nchunk) {
    __shared__ int cnt[256];                 // nbkt <= 256
    const int t = threadIdx.x, b = blockIdx.x;
    for (int i = t; i < nbkt; i += 256) cnt[i] = 0;
    __syncthreads();
#pragma unroll
    for (int it = 0; it < CHUNK / 1024; ++it) {
        int idx = b * CHUNK + it * 1024 + t * 4;
        if (idx + 3 < e) {
            int4 d = *(const int4*)(dst + idx);
            atomicAdd(&cnt[d.x >> BKTSH], 1);
            atomicAdd(&cnt[d.y >> BKTSH], 1);
            atomicAdd(&cnt[d.z >> BKTSH], 1);
            atomicAdd(&cnt[d.w >> BKTSH], 1);
        } else {
            for (int i = idx; i < e && i < idx + 4; ++i)
                atomicAdd(&cnt[dst[i] >> BKTSH], 1);
        }
    }
    __syncthreads();
    for (int i = t; i < nbkt; i += 256) H[i * nchunk + b] = cnt[i];
}

// ---- flat exclusive scan over H (len = nbkt*nchunk), 1024/block ---------

__global__ __launch_bounds__(256) void k_scanA(const int* __restrict__ in,
                                               int* __restrict__ outp,
                                               int* __restrict__ bsum, int n) {
    __shared__ int sh[256];
    const int t = threadIdx.x;
    const int base = blockIdx.x * SCAN_ELEMS + t * 4;
    int v[4];
    int s = 0;
#pragma unroll
    for (int k = 0; k < 4; k++) {
        int i = base + k;
        v[k] = (i < n) ? in[i] : 0;
        s += v[k];
    }
    sh[t] = s;
    __syncthreads();
#pragma unroll
    for (int off = 1; off < 256; off <<= 1) {
        int add = (t >= off) ? sh[t - off] : 0;
        __syncthreads();
        sh[t] += add;
        __syncthreads();
    }
    int run = sh[t] - s;
#pragma unroll
    for (int k = 0; k < 4; k++) {
        int i = base + k;
        if (i < n) outp[i] = run;
        run += v[k];
    }
    if (t == 255) bsum[blockIdx.x] = sh[255];
}

__global__ __launch_bounds__(128) void k_scan2(int* __restrict__ bsum, int nb) {
    __shared__ int sh[128];
    const int t = threadIdx.x;
    int own = (t < nb) ? bsum[t] : 0;
    sh[t] = own;
    __syncthreads();
#pragma unroll
    for (int off = 1; off < 128; off <<= 1) {
        int add = (t >= off) ? sh[t - off] : 0;
        __syncthreads();
        sh[t] += add;
        __syncthreads();
    }
    if (t < nb) bsum[t] = sh[t] - own;
}

// ---- pass 1b: scatter edges into bucket-grouped order (packed 4B) -------
// Writes per bucket per chunk are contiguous runs (~40x4B) -> coalesced.

__global__ __launch_bounds__(256) void k_bucket_scatter(
        const int* __restrict__ src, const int* __restrict__ dst,
        const int* __restrict__ Hs, const int* __restrict__ bsum,
        int* __restrict__ packed, int e, int nbkt, int nchunk) {
    __shared__ int off[256];
    __shared__ int lc[256];
    const int t = threadIdx.x, b = blockIdx.x;
    for (int i = t; i < nbkt; i += 256) {
        int idx = i * nchunk + b;
        off[i] = Hs[idx] + bsum[idx >> 10];
        lc[i] = 0;
    }
    __syncthreads();
#pragma unroll
    for (int it = 0; it < CHUNK / 1024; ++it) {
        int idx = b * CHUNK + it * 1024 + t * 4;
        if (idx + 3 < e) {
            int4 d = *(const int4*)(dst + idx);
            int4 s = *(const int4*)(src + idx);
            int b0 = d.x >> BKTSH, b1 = d.y >> BKTSH;
            int b2 = d.z >> BKTSH, b3 = d.w >> BKTSH;
            int r0 = atomicAdd(&lc[b0], 1);
            int r1 = atomicAdd(&lc[b1], 1);
            int r2 = atomicAdd(&lc[b2], 1);
            int r3 = atomicAdd(&lc[b3], 1);
            packed[off[b0] + r0] = s.x | ((d.x & (BKTSZ - 1)) << PSH);
            packed[off[b1] + r1] = s.y | ((d.y & (BKTSZ - 1)) << PSH);
            packed[off[b2] + r2] = s.z | ((d.z & (BKTSZ - 1)) << PSH);
            packed[off[b3] + r3] = s.w | ((d.w & (BKTSZ - 1)) << PSH);
        } else {
            for (int i = idx; i < e && i < idx + 4; ++i) {
                int dd = dst[i];
                int bk = dd >> BKTSH;
                int r = atomicAdd(&lc[bk], 1);
                packed[off[bk] + r] = src[i] | ((dd & (BKTSZ - 1)) << PSH);
            }
        }
    }
}

// ---- pass 2: per-bucket local CSR: deg/rowptr/dinv in LDS, place edges --
// All writes land in the bucket's own ~25KB segment (L2-hot, write-back).

__global__ __launch_bounds__(256) void k_csr_build(
        const int* __restrict__ packed, const int* __restrict__ Hs,
        const int* __restrict__ bsum, int* __restrict__ rowptr,
        float* __restrict__ dinv, int* __restrict__ csr,
        int e, int n, int nbkt, int nchunk) {
    __shared__ int cnt[BKTSZ];
    __shared__ int pref[BKTSZ];
    __shared__ int ssum[256];
    __shared__ int cnt2[BKTSZ];
    const int t = threadIdx.x, bkt = blockIdx.x;
    int i0 = bkt * nchunk;
    int segStart = Hs[i0] + bsum[i0 >> 10];
    int segEnd = e;
    if (bkt + 1 < nbkt) {
        int i1 = (bkt + 1) * nchunk;
        segEnd = Hs[i1] + bsum[i1 >> 10];
    }
    cnt[t] = 0; cnt[t + 256] = 0;
    cnt2[t] = 0; cnt2[t + 256] = 0;
    __syncthreads();
    for (int j = segStart + t; j < segEnd; j += 256)
        atomicAdd(&cnt[(packed[j] >> PSH) & (BKTSZ - 1)], 1);
    __syncthreads();
    // exclusive scan of cnt[512] with 256 threads (pair per thread)
    int a0 = cnt[2 * t], a1 = cnt[2 * t + 1];
    int s = a0 + a1;
    ssum[t] = s;
    __syncthreads();
#pragma unroll
    for (int off = 1; off < 256; off <<= 1) {
        int add = (t >= off) ? ssum[t - off] : 0;
        __syncthreads();
        ssum[t] += add;
        __syncthreads();
    }
    int p = ssum[t] - s;
    pref[2 * t] = p;
    pref[2 * t + 1] = p + a0;
    __syncthreads();
    for (int i = t; i < BKTSZ; i += 256) {
        int node = bkt * BKTSZ + i;
        if (node < n) {
            rowptr[node] = segStart + pref[i];
            dinv[node] = rsqrtf((float)(cnt[i] + 1));   // +1 self-loop
        }
    }
    if (bkt == 0 && t == 0) rowptr[n] = e;
    for (int j = segStart + t; j < segEnd; j += 256) {
        int pk = packed[j];
        int ld = (pk >> PSH) & (BKTSZ - 1);
        int r = atomicAdd(&cnt2[ld], 1);
        csr[segStart + pref[ld] + r] = pk & PMASK;
    }
}

// ---- per-layer dense transform: h' = ((relu?)act @ W) * dinv[row], fp16 -
// (norm trick: dinv[s]*dinv[d] folds into h' and a final dv scale ->
//  CSR carries no weights.)

template <int K, bool RELU>
__global__ __launch_bounds__(256) void k_gemm(
        const float* __restrict__ act, const float* __restrict__ W,
        const float* __restrict__ dinv, __half* __restrict__ h, int n_nodes) {
    __shared__ float Wsh[K * HID];
    __shared__ float Ash[16 * K];
    const int t = threadIdx.x;
    const int n0 = blockIdx.x * 16;

    for (int i = t; i < K * HID; i += 256) Wsh[i] = W[i];
    const long long lim = (long long)(n_nodes - n0) * K;
    for (int i = t; i < 16 * K; i += 256) {
        float v = (i < lim) ? act[(size_t)n0 * K + i] : 0.0f;
        if (RELU) v = fmaxf(v, 0.0f);
        Ash[i] = v;
    }
    __syncthreads();

    const int c = t & 63;       // output channel
    const int g = t >> 6;       // node sub-group 0..3, 4 nodes each
    float acc[4] = {0.0f, 0.0f, 0.0f, 0.0f};
#pragma unroll 8
    for (int k = 0; k < K; k++) {
        float w = Wsh[k * HID + c];
#pragma unroll
        for (int i = 0; i < 4; i++) acc[i] += Ash[(g * 4 + i) * K + k] * w;
    }
#pragma unroll
    for (int i = 0; i < 4; i++) {
        int n = n0 + g * 4 + i;
        if (n < n_nodes) h[(size_t)n * HID + c] = __float2half(acc[i] * dinv[n]);
    }
}

// ---- CSR aggregate: weightless. agg = b + dv*(h'[d] + sum h'[s]) --------

__device__ __forceinline__ float4 h4_to_f4(int2 raw) {
    __half2 p0 = *(__half2*)&raw.x;
    __half2 p1 = *(__half2*)&raw.y;
    float2 f0 = __half22float2(p0);
    float2 f1 = __half22float2(p1);
    return make_float4(f0.x, f0.y, f1.x, f1.y);
}

__global__ __launch_bounds__(256) void k_aggregate(
        const int* __restrict__ rowptr, const int* __restrict__ csr,
        const __half* __restrict__ h, const float* __restrict__ b,
        const float* __restrict__ dinv, float* __restrict__ agg, int n_nodes) {
    int gtid = blockIdx.x * 256 + threadIdx.x;
    int node = (gtid >> 6) * 4 + ((threadIdx.x >> 4) & 3);
    int l16 = threadIdx.x & 15;
    if (node >= n_nodes) return;
    int beg = rowptr[node], end = rowptr[node + 1];
    const int2* h8 = (const int2*)h;         // 4 halves per int2; 16 per row
    const float4* b4 = (const float4*)b;
    float dv = dinv[node];
    float4 inner = h4_to_f4(h8[(size_t)node * 16 + l16]);   // self h'
    int j = beg;
    for (; j + 3 < end; j += 4) {
        int s0 = csr[j], s1 = csr[j + 1], s2 = csr[j + 2], s3 = csr[j + 3];
        float4 v0 = h4_to_f4(h8[(size_t)s0 * 16 + l16]);
        float4 v1 = h4_to_f4(h8[(size_t)s1 * 16 + l16]);
        float4 v2 = h4_to_f4(h8[(size_t)s2 * 16 + l16]);
        float4 v3 = h4_to_f4(h8[(size_t)s3 * 16 + l16]);
        inner.x += v0.x + v1.x + v2.x + v3.x;
        inner.y += v0.y + v1.y + v2.y + v3.y;
        inner.z += v0.z + v1.z + v2.z + v3.z;
        inner.w += v0.w + v1.w + v2.w + v3.w;
    }
    for (; j < end; j++) {
        float4 v = h4_to_f4(h8[(size_t)csr[j] * 16 + l16]);
        inner.x += v.x; inner.y += v.y; inner.z += v.z; inner.w += v.w;
    }
    float4 bb = b4[l16];
    float4 acc = make_float4(bb.x + dv * inner.x, bb.y + dv * inner.y,
                             bb.z + dv * inner.z, bb.w + dv * inner.w);
    ((float4*)agg)[(size_t)node * 16 + l16] = acc;
}

// ---- fused mean-pool + head: one block per graph, batch sorted ----------

__global__ __launch_bounds__(256) void k_pool_head(
        const float* __restrict__ agg, const int* __restrict__ batch,
        const float* __restrict__ Wl, const float* __restrict__ bl,
        float* __restrict__ out, int n_nodes) {
    int g = blockIdx.x;
    int lo = 0, hi = n_nodes;
    while (lo < hi) { int m = (lo + hi) >> 1; if (batch[m] < g) lo = m + 1; else hi = m; }
    int nstart = lo;
    hi = n_nodes;
    while (lo < hi) { int m = (lo + hi) >> 1; if (batch[m] < g + 1) lo = m + 1; else hi = m; }
    int nend = lo;

    int c = threadIdx.x & 63, part = threadIdx.x >> 6;
    float acc = 0.0f;
    for (int n = nstart + part; n < nend; n += 4)
        acc += agg[(size_t)n * HID + c];

    __shared__ float red[4][64];
    __shared__ float hd[128];
    red[part][c] = acc;
    __syncthreads();
    if (threadIdx.x < 64) {
        float cntf = (float)(nend - nstart);
        float pooled = (red[0][c] + red[1][c] + red[2][c] + red[3][c])
                       / fmaxf(cntf, 1.0f);
        hd[c] = pooled * Wl[c * 2 + 0];
        hd[64 + c] = pooled * Wl[c * 2 + 1];
    }
    __syncthreads();
    if (threadIdx.x < 2) {
        float s = 0.0f;
        for (int k = 0; k < 64; k++) s += hd[threadIdx.x * 64 + k];
        out[g * 2 + threadIdx.x] = s + bl[threadIdx.x];
    }
}

// -------------------------------------------------------------------------

extern "C" void kernel_launch(void* const* d_in, const int* in_sizes, int n_in,
                              void* d_out, int out_size, void* d_ws, size_t ws_size,
                              hipStream_t stream) {
    const float* x     = (const float*)d_in[0];
    const int*   ei    = (const int*)d_in[1];
    const int*   batch = (const int*)d_in[2];
    const float* W1    = (const float*)d_in[3];
    const float* b1    = (const float*)d_in[4];
    const float* W2    = (const float*)d_in[5];
    const float* b2    = (const float*)d_in[6];
    const float* W3    = (const float*)d_in[7];
    const float* b3    = (const float*)d_in[8];
    const float* Wl    = (const float*)d_in[9];
    const float* bl    = (const float*)d_in[10];
    float* out = (float*)d_out;

    const int N = in_sizes[0] / 7;     // 100000
    const int E = in_sizes[1] / 2;     // 1250000
    const int* src = ei;
    const int* dst = ei + E;

    const int nbkt   = (N + BKTSZ - 1) >> BKTSH;          // 196
    const int nchunk = (E + CHUNK - 1) / CHUNK;           // 153
    const int lenH   = nbkt * nchunk;                     // ~30k

    // workspace carve-out (256B aligned)
    char* ws = (char*)d_ws;
    size_t off = 0;
    auto carve = [&](size_t bytes) {
        void* p = ws + off;
        off = (off + bytes + 255) & ~(size_t)255;
        return p;
    };
    int*    H      = (int*)carve((size_t)lenH * 4);
    int*    Hs     = (int*)carve((size_t)lenH * 4);
    int*    bsumA  = (int*)carve(512 * 4);
    int*    packed = (int*)carve((size_t)E * 4);
    int*    csr    = (int*)carve((size_t)E * 4);
    int*    rowptr = (int*)carve((size_t)(N + 1) * 4);
    float*  dinv   = (float*)carve((size_t)N * 4);
    __half* bufH   = (__half*)carve((size_t)N * HID * 2);
    float*  bufA   = (float*)carve((size_t)N * HID * 4);

    const int nb_gemm  = (N + 15) / 16;
    const int nb_agg   = (N + 15) / 16;
    const int nb_scanA = (lenH + SCAN_ELEMS - 1) / SCAN_ELEMS;   // 30

    // ---- CSR build: LDS-bucketed counting sort (no global atomics)
    k_bucket_count<<<nchunk, 256, 0, stream>>>(dst, H, E, nbkt, nchunk);
    k_scanA<<<nb_scanA, 256, 0, stream>>>(H, Hs, bsumA, lenH);
    k_scan2<<<1, 128, 0, stream>>>(bsumA, nb_scanA);
    k_bucket_scatter<<<nchunk, 256, 0, stream>>>(src, dst, Hs, bsumA, packed,
                                                 E, nbkt, nchunk);
    k_csr_build<<<nbkt, 256, 0, stream>>>(packed, Hs, bsumA, rowptr, dinv, csr,
                                          E, N, nbkt, nchunk);

    // ---- layer 1: x (N x 7) -> bufH (h', fp16); aggregate -> bufA
    k_gemm<7, false><<<nb_gemm, 256, 0, stream>>>(x, W1, dinv, bufH, N);
    k_aggregate<<<nb_agg, 256, 0, stream>>>(rowptr, csr, bufH, b1, dinv, bufA, N);

    // ---- layer 2: relu(bufA) @ W2 -> bufH; aggregate -> bufA
    k_gemm<HID, true><<<nb_gemm, 256, 0, stream>>>(bufA, W2, dinv, bufH, N);
    k_aggregate<<<nb_agg, 256, 0, stream>>>(rowptr, csr, bufH, b2, dinv, bufA, N);

    // ---- layer 3
    k_gemm<HID, true><<<nb_gemm, 256, 0, stream>>>(bufA, W3, dinv, bufH, N);
    k_aggregate<<<nb_agg, 256, 0, stream>>>(rowptr, csr, bufH, b3, dinv, bufA, N);

    // ---- fused mean-pool + head (one block per graph)
    k_pool_head<<<NGRAPHS, 256, 0, stream>>>(bufA, batch, Wl, bl, out, N);
}

// Round 11
// 271.195 us; speedup vs baseline: 1.5095x; 1.1645x over previous
//
#include <hip/hip_runtime.h>
#include <hip/hip_fp16.h>

#define HID 64
#define NGRAPHS 256
#define CHUNK 8192        // edges per pass-1 block
#define BKTSZ 512         // nodes per coarse bucket
#define BKTSH 9
#define PSH 17            // src fits in 17 bits (N <= 131072)
#define PMASK 0x1FFFF
#define SCAN_ELEMS 1024

typedef _Float16 half8 __attribute__((ext_vector_type(8)));
typedef float f32x4 __attribute__((ext_vector_type(4)));

// R6-R9 measured: scattered global atomics / scattered small stores write
// through ~64B lines at ~0.9 TB/s (memory-side, parallelism-invariant).
// CSR build keeps contended counters in LDS, writes coalesced runs only.

// ---- pass 1a: per-chunk coarse histogram (LDS) -> H[bkt*nchunk + chunk] --

__global__ __launch_bounds__(256) void k_bucket_count(
        const int* __restrict__ dst, int* __restrict__ H,
        int e, int nbkt, int nchunk) {
    __shared__ int cnt[256];                 // nbkt <= 256
    const int t = threadIdx.x, b = blockIdx.x;
    for (int i = t; i < nbkt; i += 256) cnt[i] = 0;
    __syncthreads();
#pragma unroll
    for (int it = 0; it < CHUNK / 1024; ++it) {
        int idx = b * CHUNK + it * 1024 + t * 4;
        if (idx + 3 < e) {
            int4 d = *(const int4*)(dst + idx);
            atomicAdd(&cnt[d.x >> BKTSH], 1);
            atomicAdd(&cnt[d.y >> BKTSH], 1);
            atomicAdd(&cnt[d.z >> BKTSH], 1);
            atomicAdd(&cnt[d.w >> BKTSH], 1);
        } else {
            for (int i = idx; i < e && i < idx + 4; ++i)
                atomicAdd(&cnt[dst[i] >> BKTSH], 1);
        }
    }
    __syncthreads();
    for (int i = t; i < nbkt; i += 256) H[i * nchunk + b] = cnt[i];
}

// ---- flat exclusive scan over H (len = nbkt*nchunk) ---------------------

__global__ __launch_bounds__(256) void k_scanA(const int* __restrict__ in,
                                               int* __restrict__ outp,
                                               int* __restrict__ bsum, int n) {
    __shared__ int sh[256];
    const int t = threadIdx.x;
    const int base = blockIdx.x * SCAN_ELEMS + t * 4;
    int v[4];
    int s = 0;
#pragma unroll
    for (int k = 0; k < 4; k++) {
        int i = base + k;
        v[k] = (i < n) ? in[i] : 0;
        s += v[k];
    }
    sh[t] = s;
    __syncthreads();
#pragma unroll
    for (int off = 1; off < 256; off <<= 1) {
        int add = (t >= off) ? sh[t - off] : 0;
        __syncthreads();
        sh[t] += add;
        __syncthreads();
    }
    int run = sh[t] - s;
#pragma unroll
    for (int k = 0; k < 4; k++) {
        int i = base + k;
        if (i < n) outp[i] = run;
        run += v[k];
    }
    if (t == 255) bsum[blockIdx.x] = sh[255];
}

__global__ __launch_bounds__(128) void k_scan2(int* __restrict__ bsum, int nb) {
    __shared__ int sh[128];
    const int t = threadIdx.x;
    int own = (t < nb) ? bsum[t] : 0;
    sh[t] = own;
    __syncthreads();
#pragma unroll
    for (int off = 1; off < 128; off <<= 1) {
        int add = (t >= off) ? sh[t - off] : 0;
        __syncthreads();
        sh[t] += add;
        __syncthreads();
    }
    if (t < nb) bsum[t] = sh[t] - own;
}

// ---- pass 1b: scatter edges into bucket-grouped order (packed 4B) -------

__global__ __launch_bounds__(256) void k_bucket_scatter(
        const int* __restrict__ src, const int* __restrict__ dst,
        const int* __restrict__ Hs, const int* __restrict__ bsum,
        int* __restrict__ packed, int e, int nbkt, int nchunk) {
    __shared__ int off[256];
    __shared__ int lc[256];
    const int t = threadIdx.x, b = blockIdx.x;
    for (int i = t; i < nbkt; i += 256) {
        int idx = i * nchunk + b;
        off[i] = Hs[idx] + bsum[idx >> 10];
        lc[i] = 0;
    }
    __syncthreads();
#pragma unroll
    for (int it = 0; it < CHUNK / 1024; ++it) {
        int idx = b * CHUNK + it * 1024 + t * 4;
        if (idx + 3 < e) {
            int4 d = *(const int4*)(dst + idx);
            int4 s = *(const int4*)(src + idx);
            int b0 = d.x >> BKTSH, b1 = d.y >> BKTSH;
            int b2 = d.z >> BKTSH, b3 = d.w >> BKTSH;
            int r0 = atomicAdd(&lc[b0], 1);
            int r1 = atomicAdd(&lc[b1], 1);
            int r2 = atomicAdd(&lc[b2], 1);
            int r3 = atomicAdd(&lc[b3], 1);
            packed[off[b0] + r0] = s.x | ((d.x & (BKTSZ - 1)) << PSH);
            packed[off[b1] + r1] = s.y | ((d.y & (BKTSZ - 1)) << PSH);
            packed[off[b2] + r2] = s.z | ((d.z & (BKTSZ - 1)) << PSH);
            packed[off[b3] + r3] = s.w | ((d.w & (BKTSZ - 1)) << PSH);
        } else {
            for (int i = idx; i < e && i < idx + 4; ++i) {
                int dd = dst[i];
                int bk = dd >> BKTSH;
                int r = atomicAdd(&lc[bk], 1);
                packed[off[bk] + r] = src[i] | ((dd & (BKTSZ - 1)) << PSH);
            }
        }
    }
}

// ---- pass 2: per-bucket local CSR: deg/rowptr/dinv in LDS ---------------

__global__ __launch_bounds__(256) void k_csr_build(
        const int* __restrict__ packed, const int* __restrict__ Hs,
        const int* __restrict__ bsum, int* __restrict__ rowptr,
        float* __restrict__ dinv, int* __restrict__ csr,
        int e, int n, int nbkt, int nchunk) {
    __shared__ int cnt[BKTSZ];
    __shared__ int pref[BKTSZ];
    __shared__ int ssum[256];
    __shared__ int cnt2[BKTSZ];
    const int t = threadIdx.x, bkt = blockIdx.x;
    int i0 = bkt * nchunk;
    int segStart = Hs[i0] + bsum[i0 >> 10];
    int segEnd = e;
    if (bkt + 1 < nbkt) {
        int i1 = (bkt + 1) * nchunk;
        segEnd = Hs[i1] + bsum[i1 >> 10];
    }
    cnt[t] = 0; cnt[t + 256] = 0;
    cnt2[t] = 0; cnt2[t + 256] = 0;
    __syncthreads();
    for (int j = segStart + t; j < segEnd; j += 256)
        atomicAdd(&cnt[(packed[j] >> PSH) & (BKTSZ - 1)], 1);
    __syncthreads();
    int a0 = cnt[2 * t], a1 = cnt[2 * t + 1];
    int s = a0 + a1;
    ssum[t] = s;
    __syncthreads();
#pragma unroll
    for (int off = 1; off < 256; off <<= 1) {
        int add = (t >= off) ? ssum[t - off] : 0;
        __syncthreads();
        ssum[t] += add;
        __syncthreads();
    }
    int p = ssum[t] - s;
    pref[2 * t] = p;
    pref[2 * t + 1] = p + a0;
    __syncthreads();
    for (int i = t; i < BKTSZ; i += 256) {
        int node = bkt * BKTSZ + i;
        if (node < n) {
            rowptr[node] = segStart + pref[i];
            dinv[node] = rsqrtf((float)(cnt[i] + 1));   // +1 self-loop
        }
    }
    if (bkt == 0 && t == 0) rowptr[n] = e;
    for (int j = segStart + t; j < segEnd; j += 256) {
        int pk = packed[j];
        int ld = (pk >> PSH) & (BKTSZ - 1);
        int r = atomicAdd(&cnt2[ld], 1);
        csr[segStart + pref[ld] + r] = pk & PMASK;
    }
}

// ---- prep: repack W (fp32 64x64) into 16x16x32-f16 B-fragment layout ----
// frag pos p in [0,512): kt=p>>8, ctile=(p>>6)&3, lane=p&63.
// lane holds B[k = kt*32 + (lane>>4)*8 + j][ch = ctile*16 + (lane&15)].

__global__ __launch_bounds__(256) void k_prepW(const float* __restrict__ W2,
                                               const float* __restrict__ W3,
                                               __half* __restrict__ Wf2,
                                               __half* __restrict__ Wf3) {
    int p = blockIdx.x * 256 + threadIdx.x;
    if (p >= 512) return;
    int kt = p >> 8, c = (p >> 6) & 3, lane = p & 63;
    int quad = lane >> 4, m = lane & 15;
#pragma unroll
    for (int j = 0; j < 8; ++j) {
        int k = kt * 32 + quad * 8 + j;
        int ch = c * 16 + m;
        Wf2[(size_t)p * 8 + j] = __float2half(W2[k * HID + ch]);
        Wf3[(size_t)p * 8 + j] = __float2half(W3[k * HID + ch]);
    }
}

// ---- layer-1 dense transform (K=7, fp32 in): h' = (x @ W1) * dinv -------

template <int K, bool RELU>
__global__ __launch_bounds__(256) void k_gemm(
        const float* __restrict__ act, const float* __restrict__ W,
        const float* __restrict__ dinv, __half* __restrict__ h, int n_nodes) {
    __shared__ float Wsh[K * HID];
    __shared__ float Ash[16 * K];
    const int t = threadIdx.x;
    const int n0 = blockIdx.x * 16;

    for (int i = t; i < K * HID; i += 256) Wsh[i] = W[i];
    const long long lim = (long long)(n_nodes - n0) * K;
    for (int i = t; i < 16 * K; i += 256) {
        float v = (i < lim) ? act[(size_t)n0 * K + i] : 0.0f;
        if (RELU) v = fmaxf(v, 0.0f);
        Ash[i] = v;
    }
    __syncthreads();

    const int c = t & 63;
    const int g = t >> 6;
    float acc[4] = {0.0f, 0.0f, 0.0f, 0.0f};
#pragma unroll
    for (int k = 0; k < K; k++) {
        float w = Wsh[k * HID + c];
#pragma unroll
        for (int i = 0; i < 4; i++) acc[i] += Ash[(g * 4 + i) * K + k] * w;
    }
#pragma unroll
    for (int i = 0; i < 4; i++) {
        int n = n0 + g * 4 + i;
        if (n < n_nodes) h[(size_t)n * HID + c] = __float2half(acc[i] * dinv[n]);
    }
}

// ---- layers 2/3: MFMA gemm, no LDS. h' = (relu(act) @ W) * dinv, fp16 ---
// A-frag: lane holds act[n0 + (lane&15)][kt*32 + (lane>>4)*8 + j] (16B load).
// D: col=lane&15 (ch), row=(lane>>4)*4+reg (node). [verified m89/m120 maps]

template <bool RELU>
__global__ __launch_bounds__(256) void k_gemm_mfma(
        const __half* __restrict__ act, const __half* __restrict__ Wf,
        const float* __restrict__ dinv, __half* __restrict__ h, int n_nodes) {
    const int wave = threadIdx.x >> 6;
    const int lane = threadIdx.x & 63;
    const int quad = lane >> 4, m = lane & 15;
    const int n0 = blockIdx.x * 64 + wave * 16;
    if (n0 >= n_nodes) return;            // wave-uniform

    const half8* Wf8 = (const half8*)Wf;
    f32x4 zero = {0.0f, 0.0f, 0.0f, 0.0f};
    f32x4 acc[4] = {zero, zero, zero, zero};
#pragma unroll
    for (int kt = 0; kt < 2; ++kt) {
        half8 a = *(const half8*)(act + (size_t)(n0 + m) * HID + kt * 32 + quad * 8);
        if (RELU) {
#pragma unroll
            for (int j = 0; j < 8; ++j)
                a[j] = a[j] > (_Float16)0 ? a[j] : (_Float16)0;
        }
#pragma unroll
        for (int c = 0; c < 4; ++c) {
            half8 b = Wf8[(kt * 4 + c) * 64 + lane];
            acc[c] = __builtin_amdgcn_mfma_f32_16x16x32_f16(a, b, acc[c], 0, 0, 0);
        }
    }
#pragma unroll
    for (int r = 0; r < 4; ++r) {
        int node = n0 + quad * 4 + r;
        if (node < n_nodes) {
            float dv = dinv[node];
#pragma unroll
            for (int c = 0; c < 4; ++c)
                h[(size_t)node * HID + c * 16 + m] = __float2half(acc[c][r] * dv);
        }
    }
}

// ---- CSR aggregate: weightless, 8-wide, fp16 in/out ---------------------
// agg = b + dv*(h'[d] + sum h'[s]);  fp32 accumulation.

__device__ __forceinline__ float4 h4_to_f4(int2 raw) {
    __half2 p0 = *(__half2*)&raw.x;
    __half2 p1 = *(__half2*)&raw.y;
    float2 f0 = __half22float2(p0);
    float2 f1 = __half22float2(p1);
    return make_float4(f0.x, f0.y, f1.x, f1.y);
}

__global__ __launch_bounds__(256) void k_aggregate(
        const int* __restrict__ rowptr, const int* __restrict__ csr,
        const __half* __restrict__ h, const float* __restrict__ b,
        const float* __restrict__ dinv, __half* __restrict__ agg, int n_nodes) {
    int gtid = blockIdx.x * 256 + threadIdx.x;
    int node = (gtid >> 6) * 4 + ((threadIdx.x >> 4) & 3);
    int l16 = threadIdx.x & 15;
    if (node >= n_nodes) return;
    int beg = rowptr[node], end = rowptr[node + 1];
    const int2* h8 = (const int2*)h;
    const float4* b4 = (const float4*)b;
    float dv = dinv[node];
    float4 inner = h4_to_f4(h8[(size_t)node * 16 + l16]);   // self h'
    int j = beg;
    for (; j + 7 < end; j += 8) {                  // 8 outstanding gathers
        int s[8];
#pragma unroll
        for (int q = 0; q < 8; ++q) s[q] = csr[j + q];
        int2 r[8];
#pragma unroll
        for (int q = 0; q < 8; ++q) r[q] = h8[(size_t)s[q] * 16 + l16];
#pragma unroll
        for (int q = 0; q < 8; ++q) {
            float4 v = h4_to_f4(r[q]);
            inner.x += v.x; inner.y += v.y; inner.z += v.z; inner.w += v.w;
        }
    }
    for (; j + 3 < end; j += 4) {
        int s0 = csr[j], s1 = csr[j + 1], s2 = csr[j + 2], s3 = csr[j + 3];
        float4 v0 = h4_to_f4(h8[(size_t)s0 * 16 + l16]);
        float4 v1 = h4_to_f4(h8[(size_t)s1 * 16 + l16]);
        float4 v2 = h4_to_f4(h8[(size_t)s2 * 16 + l16]);
        float4 v3 = h4_to_f4(h8[(size_t)s3 * 16 + l16]);
        inner.x += v0.x + v1.x + v2.x + v3.x;
        inner.y += v0.y + v1.y + v2.y + v3.y;
        inner.z += v0.z + v1.z + v2.z + v3.z;
        inner.w += v0.w + v1.w + v2.w + v3.w;
    }
    for (; j < end; j++) {
        float4 v = h4_to_f4(h8[(size_t)csr[j] * 16 + l16]);
        inner.x += v.x; inner.y += v.y; inner.z += v.z; inner.w += v.w;
    }
    float4 bb = b4[l16];
    __half2 p0 = __floats2half2_rn(bb.x + dv * inner.x, bb.y + dv * inner.y);
    __half2 p1 = __floats2half2_rn(bb.z + dv * inner.z, bb.w + dv * inner.w);
    int2 outv;
    outv.x = *(int*)&p0;
    outv.y = *(int*)&p1;
    ((int2*)agg)[(size_t)node * 16 + l16] = outv;
}

// ---- fused mean-pool + head: one block per graph, batch sorted ----------

__global__ __launch_bounds__(256) void k_pool_head(
        const __half* __restrict__ agg, const int* __restrict__ batch,
        const float* __restrict__ Wl, const float* __restrict__ bl,
        float* __restrict__ out, int n_nodes) {
    int g = blockIdx.x;
    int lo = 0, hi = n_nodes;
    while (lo < hi) { int m = (lo + hi) >> 1; if (batch[m] < g) lo = m + 1; else hi = m; }
    int nstart = lo;
    hi = n_nodes;
    while (lo < hi) { int m = (lo + hi) >> 1; if (batch[m] < g + 1) lo = m + 1; else hi = m; }
    int nend = lo;

    int c = threadIdx.x & 63, part = threadIdx.x >> 6;
    float acc = 0.0f;
    for (int n = nstart + part; n < nend; n += 4)
        acc += __half2float(agg[(size_t)n * HID + c]);

    __shared__ float red[4][64];
    __shared__ float hd[128];
    red[part][c] = acc;
    __syncthreads();
    if (threadIdx.x < 64) {
        float cntf = (float)(nend - nstart);
        float pooled = (red[0][c] + red[1][c] + red[2][c] + red[3][c])
                       / fmaxf(cntf, 1.0f);
        hd[c] = pooled * Wl[c * 2 + 0];
        hd[64 + c] = pooled * Wl[c * 2 + 1];
    }
    __syncthreads();
    if (threadIdx.x < 2) {
        float s = 0.0f;
        for (int k = 0; k < 64; k++) s += hd[threadIdx.x * 64 + k];
        out[g * 2 + threadIdx.x] = s + bl[threadIdx.x];
    }
}

// -------------------------------------------------------------------------

extern "C" void kernel_launch(void* const* d_in, const int* in_sizes, int n_in,
                              void* d_out, int out_size, void* d_ws, size_t ws_size,
                              hipStream_t stream) {
    const float* x     = (const float*)d_in[0];
    const int*   ei    = (const int*)d_in[1];
    const int*   batch = (const int*)d_in[2];
    const float* W1    = (const float*)d_in[3];
    const float* b1    = (const float*)d_in[4];
    const float* W2    = (const float*)d_in[5];
    const float* b2    = (const float*)d_in[6];
    const float* W3    = (const float*)d_in[7];
    const float* b3    = (const float*)d_in[8];
    const float* Wl    = (const float*)d_in[9];
    const float* bl    = (const float*)d_in[10];
    float* out = (float*)d_out;

    const int N = in_sizes[0] / 7;     // 100000
    const int E = in_sizes[1] / 2;     // 1250000
    const int* src = ei;
    const int* dst = ei + E;

    const int nbkt   = (N + BKTSZ - 1) >> BKTSH;          // 196
    const int nchunk = (E + CHUNK - 1) / CHUNK;           // 153
    const int lenH   = nbkt * nchunk;

    // workspace carve-out (256B aligned)
    char* ws = (char*)d_ws;
    size_t off = 0;
    auto carve = [&](size_t bytes) {
        void* p = ws + off;
        off = (off + bytes + 255) & ~(size_t)255;
        return p;
    };
    int*    H      = (int*)carve((size_t)lenH * 4);
    int*    Hs     = (int*)carve((size_t)lenH * 4);
    int*    bsumA  = (int*)carve(512 * 4);
    int*    packed = (int*)carve((size_t)E * 4);
    int*    csr    = (int*)carve((size_t)E * 4);
    int*    rowptr = (int*)carve((size_t)(N + 1) * 4);
    float*  dinv   = (float*)carve((size_t)N * 4);
    __half* Wf2    = (__half*)carve(4096 * 2);
    __half* Wf3    = (__half*)carve(4096 * 2);
    __half* bufH   = (__half*)carve((size_t)(N + 64) * HID * 2);  // +64 pad rows
    __half* bufA   = (__half*)carve((size_t)(N + 64) * HID * 2);

    const int nb_gemm7 = (N + 15) / 16;
    const int nb_mfma  = (N + 63) / 64;
    const int nb_agg   = (N + 15) / 16;
    const int nb_scanA = (lenH + SCAN_ELEMS - 1) / SCAN_ELEMS;

    // ---- W frag repack (independent; overlaps nothing but is ~2us)
    k_prepW<<<2, 256, 0, stream>>>(W2, W3, Wf2, Wf3);

    // ---- CSR build: LDS-bucketed counting sort (no global atomics)
    k_bucket_count<<<nchunk, 256, 0, stream>>>(dst, H, E, nbkt, nchunk);
    k_scanA<<<nb_scanA, 256, 0, stream>>>(H, Hs, bsumA, lenH);
    k_scan2<<<1, 128, 0, stream>>>(bsumA, nb_scanA);
    k_bucket_scatter<<<nchunk, 256, 0, stream>>>(src, dst, Hs, bsumA, packed,
                                                 E, nbkt, nchunk);
    k_csr_build<<<nbkt, 256, 0, stream>>>(packed, Hs, bsumA, rowptr, dinv, csr,
                                          E, N, nbkt, nchunk);

    // ---- layer 1: x (N x 7, fp32) -> bufH (h', fp16); aggregate -> bufA
    k_gemm<7, false><<<nb_gemm7, 256, 0, stream>>>(x, W1, dinv, bufH, N);
    k_aggregate<<<nb_agg, 256, 0, stream>>>(rowptr, csr, bufH, b1, dinv, bufA, N);

    // ---- layer 2: relu(bufA) @ W2 (MFMA) -> bufH; aggregate -> bufA
    k_gemm_mfma<true><<<nb_mfma, 256, 0, stream>>>(bufA, Wf2, dinv, bufH, N);
    k_aggregate<<<nb_agg, 256, 0, stream>>>(rowptr, csr, bufH, b2, dinv, bufA, N);

    // ---- layer 3
    k_gemm_mfma<true><<<nb_mfma, 256, 0, stream>>>(bufA, Wf3, dinv, bufH, N);
    k_aggregate<<<nb_agg, 256, 0, stream>>>(rowptr, csr, bufH, b3, dinv, bufA, N);

    // ---- fused mean-pool + head (one block per graph)
    k_pool_head<<<NGRAPHS, 256, 0, stream>>>(bufA, batch, Wl, bl, out, N);
}